// Round 14
// baseline (733.429 us; speedup 1.0000x reference)
//
#include <hip/hip_runtime.h>

#define NN 16384
#define DD 16
#define KK 64
#define QQ 4            // queries per block
#define TPB 256
#define NCHUNK 8        // 8 u32 words/thread; word bit 4k+q covers j=(c*8+k)*TPB+tid
#define HIST 1024       // buckets over d2 in [0,256), width 1/4 — covers ALL pairs
#define HISTW (HIST/2)  // packed: 2 u16 counters per u32
#define LIST_MAX 768    // E[count]≈590, +7 sigma; overflow -> exact fallback
#define CAND_MAX 256

// XLA:CPU vectorized row-reduce, minor dim 16: lane halving tree. (VALIDATED r5)
__device__ __forceinline__ float halving_sumsq16(const float* v) {
    float p[16];
#pragma unroll
    for (int d = 0; d < 16; ++d) p[d] = __fmul_rn(v[d], v[d]);
    float r8[8];
#pragma unroll
    for (int j = 0; j < 8; ++j) r8[j] = __fadd_rn(p[j], p[j + 8]);
    float r4[4];
#pragma unroll
    for (int j = 0; j < 4; ++j) r4[j] = __fadd_rn(r8[j], r8[j + 4]);
    float r2[2];
#pragma unroll
    for (int j = 0; j < 2; ++j) r2[j] = __fadd_rn(r4[j], r4[j + 2]);
    return __fadd_rn(r2[0], r2[1]);
}

// d2 recipe (VALIDATED r5): f32( f32(sqi+sqj) - 2*dot ), dot = ascending-k fmaf
__device__ __forceinline__ float d2_of(const float* xi, const float* xj,
                                       float sqi, float sqj) {
    float dot = 0.0f;
#pragma unroll
    for (int d = 0; d < DD; ++d) dot = fmaf(xi[d], xj[d], dot);
    return __fsub_rn(__fadd_rn(sqi, sqj), __fmul_rn(2.0f, dot));
}

__device__ __forceinline__ int bucket_of(float d2) {
    int b = (int)__fmul_rn(d2, 4.0f);
    if (b < 0) b = 0;
    if (b >= HIST) b = HIST - 1;
    return b;
}

#define LOAD_XQ()                                                              \
    float xq[QQ][DD];                                                          \
    float sq[QQ], Tq[QQ];                                                      \
    _Pragma("unroll") for (int q = 0; q < QQ; ++q) {                           \
        const float4* p = reinterpret_cast<const float4*>(x + (iA + q) * DD);  \
        float4 a0 = p[0], a1 = p[1], a2 = p[2], a3 = p[3];                     \
        xq[q][0]=a0.x; xq[q][1]=a0.y; xq[q][2]=a0.z; xq[q][3]=a0.w;            \
        xq[q][4]=a1.x; xq[q][5]=a1.y; xq[q][6]=a1.z; xq[q][7]=a1.w;            \
        xq[q][8]=a2.x; xq[q][9]=a2.y; xq[q][10]=a2.z; xq[q][11]=a2.w;          \
        xq[q][12]=a3.x; xq[q][13]=a3.y; xq[q][14]=a3.z; xq[q][15]=a3.w;        \
        sq[q] = sqf[iA + q];                                                   \
        Tq[q] = 16.0f + sq[q] - 1.8f * sqrtf(32.0f + 4.0f * sq[q]);            \
    }

#define LOAD_XJ(j)                                                             \
    const float4* xj4 = reinterpret_cast<const float4*>(x + (j) * DD);         \
    float4 a0 = xj4[0], a1 = xj4[1], a2 = xj4[2], a3 = xj4[3];                 \
    float xj[DD] = {a0.x, a0.y, a0.z, a0.w, a1.x, a1.y, a1.z, a1.w,            \
                    a2.x, a2.y, a2.z, a2.w, a3.x, a3.y, a3.z, a3.w};

// ---------------- prep: f32 squared norms (halving tree) + copy x ----------------
__global__ void prep_kernel(const float* __restrict__ x,
                            float* __restrict__ out_x,
                            float* __restrict__ sqf) {
    int i = blockIdx.x * blockDim.x + threadIdx.x;
    if (i < NN) {
        float v[DD];
#pragma unroll
        for (int d = 0; d < DD; ++d) v[d] = x[i * DD + d];
        sqf[i] = halving_sumsq16(v);
    }
    for (int t = i; t < NN * DD; t += gridDim.x * blockDim.x) {
        out_x[t] = x[t];
    }
}

// ---------------- K1: memory-silent scan (bits in regs) + one-time harvest ----------------
__global__ __launch_bounds__(TPB) void scan_kernel(
        const float* __restrict__ x,
        const float* __restrict__ sqf,
        unsigned int* __restrict__ ws_cnt,
        unsigned short* __restrict__ ws_list) {
    __shared__ unsigned short list[QQ][LIST_MAX];   // 6 KB
    __shared__ unsigned int wcnt[TPB / 64][QQ];
    __shared__ unsigned int s_listcnt[QQ];

    const int bid = blockIdx.x;
    const int tid = threadIdx.x;
    const int lane = tid & 63;
    const int w = tid >> 6;
    const int iA = bid * QQ;

    LOAD_XQ();

    // hot loop: pure VALU + VMEM. Zero DS/atomic/shfl ops.
    unsigned int w32s[NCHUNK];
#pragma unroll
    for (int c = 0; c < NCHUNK; ++c) {
        unsigned int bits = 0;
#pragma unroll
        for (int k = 0; k < 8; ++k) {
            const int j = (c * 8 + k) * TPB + tid;
            LOAD_XJ(j);
            const float sj = sqf[j];
#pragma unroll
            for (int q = 0; q < QQ; ++q) {
                float d2 = d2_of(xq[q], xj, sq[q], sj);
                if (d2 < Tq[q]) bits |= (1u << (4 * k + q));
            }
        }
        w32s[c] = bits;
    }

    // one-time harvest (r12-B2 logic, validated): popc -> wave prefix -> scatter
    {
        unsigned int cnt[QQ] = {0, 0, 0, 0};
#pragma unroll
        for (int c = 0; c < NCHUNK; ++c)
#pragma unroll
            for (int q = 0; q < QQ; ++q)
                cnt[q] += (unsigned int)__popc(w32s[c] & (0x11111111u << q));
        unsigned int excl[QQ];
#pragma unroll
        for (int q = 0; q < QQ; ++q) {
            unsigned int v = cnt[q];
#pragma unroll
            for (int off = 1; off < 64; off <<= 1) {
                unsigned int n = __shfl_up(v, off, 64);
                if (lane >= off) v += n;
            }
            excl[q] = v - cnt[q];
            if (lane == 63) wcnt[w][q] = v;
        }
        __syncthreads();
        if (tid < QQ)
            s_listcnt[tid] = wcnt[0][tid] + wcnt[1][tid] + wcnt[2][tid] + wcnt[3][tid];
        unsigned int cur[QQ];
#pragma unroll
        for (int q = 0; q < QQ; ++q) {
            unsigned int b = 0;
            for (int ww = 0; ww < w; ++ww) b += wcnt[ww][q];
            cur[q] = b + excl[q];
        }
#pragma unroll
        for (int c = 0; c < NCHUNK; ++c) {
            unsigned int t32 = w32s[c];
            while (t32) {
                int b = __ffs(t32) - 1;
                int q = b & 3;
                int k = b >> 2;
                unsigned int pos = cur[q]++;
                if (pos < LIST_MAX)
                    list[q][pos] = (unsigned short)((c * 8 + k) * TPB + tid);
                t32 &= t32 - 1;
            }
        }
    }
    __syncthreads();

    // dump lists + raw counts to ws
    for (int q = 0; q < QQ; ++q) {
        int lc = (int)min(s_listcnt[q], (unsigned int)LIST_MAX);
        unsigned short* dst = ws_list + ((long)iA + q) * LIST_MAX;
        for (int e = tid; e < lc; e += TPB) dst[e] = list[q][e];
    }
    if (tid < QQ) ws_cnt[iA + tid] = s_listcnt[tid];
}

// ---------------- K2: select + rank + write (VALIDATED r13, unchanged) ----------------
__global__ __launch_bounds__(TPB) void select_kernel(
        const float* __restrict__ x,
        const int* __restrict__ pid,
        const float* __restrict__ sqf,
        const unsigned int* __restrict__ ws_cnt,
        const unsigned short* __restrict__ ws_list,
        float* __restrict__ out_src,
        float* __restrict__ out_dst,
        float* __restrict__ out_y,
        float* __restrict__ out_ef,
        float* __restrict__ out_mask) {
    __shared__ unsigned short list[QQ][LIST_MAX];   // 6 KB
    __shared__ unsigned int hist[QQ][HISTW];        // 8 KB
    __shared__ unsigned int cand_key[QQ][CAND_MAX]; // 4 KB
    __shared__ int cand_idx[QQ][CAND_MAX];          // 4 KB
    __shared__ unsigned int wavesum[QQ][TPB / 64];
    __shared__ int s_bsel[QQ];
    __shared__ unsigned int s_excnt[QQ], s_candcnt[QQ], s_lc[QQ];
    __shared__ int s_fb[QQ];

    const int bid = blockIdx.x;
    const int tid = threadIdx.x;
    const int lane = tid & 63;
    const int w = tid >> 6;
    const int iA = bid * QQ;

    for (int t = tid; t < QQ * HISTW; t += TPB)
        ((unsigned int*)hist)[t] = 0;
    if (tid < QQ) {
        s_excnt[tid] = 0; s_candcnt[tid] = 0; s_bsel[tid] = HIST - 1;
        s_lc[tid] = min(ws_cnt[iA + tid], (unsigned int)LIST_MAX);
    }
    LOAD_XQ();
    __syncthreads();

    for (int q = 0; q < QQ; ++q) {
        const unsigned short* src = ws_list + ((long)iA + q) * LIST_MAX;
        const int lc = (int)s_lc[q];
        for (int e = tid; e < lc; e += TPB) list[q][e] = src[e];
    }
    __syncthreads();

    // E0: exact d2 per list entry -> hist + exact count(<Tq) soundness guard
    for (int q = 0; q < QQ; ++q) {
        const int lc = (int)s_lc[q];
        unsigned int my = 0;
        for (int e = tid; e < lc; e += TPB) {
            const int j = list[q][e];
            LOAD_XJ(j);
            float d2 = d2_of(xq[q], xj, sq[q], sqf[j]);
            my += (d2 < Tq[q]) ? 1u : 0u;
            int b = bucket_of(d2);
            atomicAdd(&hist[q][b >> 1], 1u << ((b & 1) << 4));
        }
        unsigned int v = my;
#pragma unroll
        for (int off = 1; off < 64; off <<= 1) v += __shfl_xor(v, off, 64);
        if (lane == 0 && v) atomicAdd(&s_excnt[q], v);
    }
    __syncthreads();

    if (tid < QQ)
        s_fb[tid] = (ws_cnt[iA + tid] > LIST_MAX) || (s_excnt[tid] < KK + 1);
    __syncthreads();
    const int anyfb = s_fb[0] | s_fb[1] | s_fb[2] | s_fb[3];

    if (anyfb) {
#pragma unroll
        for (int q = 0; q < QQ; ++q)
            if (s_fb[q])
                for (int t = tid; t < HISTW; t += TPB) hist[q][t] = 0;
        __syncthreads();
        for (int j = tid; j < NN; j += TPB) {
            LOAD_XJ(j);
            const float sj = sqf[j];
#pragma unroll
            for (int q = 0; q < QQ; ++q) {
                if (s_fb[q] && j != iA + q) {
                    float d2 = d2_of(xq[q], xj, sq[q], sj);
                    int b = bucket_of(d2);
                    atomicAdd(&hist[q][b >> 1], 1u << ((b & 1) << 4));
                }
            }
        }
    }
    __syncthreads();

    // F: prefix-scan over packed buckets -> bucket of need-th key (VALIDATED)
    {
        unsigned int local[QQ], inc[QQ];
        unsigned int pc0[QQ], pc1[QQ], pc2[QQ], pc3[QQ];
#pragma unroll
        for (int q = 0; q < QQ; ++q) {
            unsigned int h0 = hist[q][2 * tid];
            unsigned int h1 = hist[q][2 * tid + 1];
            pc0[q] = h0 & 0xFFFFu; pc1[q] = h0 >> 16;
            pc2[q] = h1 & 0xFFFFu; pc3[q] = h1 >> 16;
            unsigned int s = pc0[q] + pc1[q] + pc2[q] + pc3[q];
            local[q] = s;
            unsigned int v = s;
#pragma unroll
            for (int off = 1; off < 64; off <<= 1) {
                unsigned int n = __shfl_up(v, off, 64);
                if (lane >= off) v += n;
            }
            inc[q] = v;
        }
        if (lane == 63)
#pragma unroll
            for (int q = 0; q < QQ; ++q) wavesum[q][w] = inc[q];
        __syncthreads();
#pragma unroll
        for (int q = 0; q < QQ; ++q) {
            const unsigned int need = s_fb[q] ? KK : (KK + 1);
            unsigned int woff = 0;
            for (int ww = 0; ww < w; ++ww) woff += wavesum[q][ww];
            unsigned int cum = inc[q] + woff;
            unsigned int prev = cum - local[q];
            if (prev < need && need <= cum) {
                unsigned int acc = prev;
                int b = 4 * tid;
                if (acc + pc0[q] < need) { acc += pc0[q]; ++b;
                    if (acc + pc1[q] < need) { acc += pc1[q]; ++b;
                        if (acc + pc2[q] < need) { acc += pc2[q]; ++b; } } }
                s_bsel[q] = b;
            }
        }
    }
    __syncthreads();

    // G: candidate gather (self excluded)
#pragma unroll
    for (int q = 0; q < QQ; ++q) {
        if (!s_fb[q]) {
            const int bsel = s_bsel[q];
            const int lc = (int)s_lc[q];
            for (int e = tid; e < lc; e += TPB) {
                const int j = list[q][e];
                LOAD_XJ(j);
                float d2 = d2_of(xq[q], xj, sq[q], sqf[j]);
                if (bucket_of(d2) <= bsel && j != iA + q) {
                    unsigned int pos = atomicAdd(&s_candcnt[q], 1u);
                    if (pos < CAND_MAX) {
                        unsigned int u = __float_as_uint(d2);
                        u ^= (u & 0x80000000u) ? 0xFFFFFFFFu : 0x80000000u;
                        cand_key[q][pos] = u;
                        cand_idx[q][pos] = j;
                    }
                }
            }
        }
    }
    if (anyfb) {
        for (int j = tid; j < NN; j += TPB) {
            LOAD_XJ(j);
            const float sj = sqf[j];
#pragma unroll
            for (int q = 0; q < QQ; ++q) {
                if (s_fb[q] && j != iA + q) {
                    float d2 = d2_of(xq[q], xj, sq[q], sj);
                    if (bucket_of(d2) <= s_bsel[q]) {
                        unsigned int pos = atomicAdd(&s_candcnt[q], 1u);
                        if (pos < CAND_MAX) {
                            unsigned int u = __float_as_uint(d2);
                            u ^= (u & 0x80000000u) ? 0xFFFFFFFFu : 0x80000000u;
                            cand_key[q][pos] = u;
                            cand_idx[q][pos] = j;
                        }
                    }
                }
            }
        }
    }
    __syncthreads();

    // H: rank by (key asc, index asc) + write outputs (VALIDATED)
    for (int q = 0; q < QQ; ++q) {
        const int iq = iA + q;
        const int mypid = pid[iq];
        int c = (int)s_candcnt[q];
        if (c > CAND_MAX) c = CAND_MAX;
        for (int t = tid; t < c; t += TPB) {
            const unsigned int kt = cand_key[q][t];
            const int jt = cand_idx[q][t];
            int rank = 0;
            for (int u = 0; u < c; ++u) {
                unsigned int ku = cand_key[q][u];
                rank += (ku < kt) || (ku == kt && cand_idx[q][u] < jt);
            }
            if (rank < KK) {
                const long e = (long)iq * KK + rank;
                out_src[e] = (float)jt;

                const float* xjp = x + jt * DD;
                float diff[DD], sum[DD];
#pragma unroll
                for (int d = 0; d < DD; ++d) {
                    float a = xjp[d], b = xq[q][d];
                    diff[d] = __fsub_rn(a, b);   // x_src - x_dst
                    sum[d]  = __fadd_rn(a, b);   // x_src + x_dst
                }
                const float s2 = halving_sumsq16(diff);    // VALIDATED tree
                const bool m = __fsqrt_rn(s2) < 6.0f;
                out_mask[e] = m ? 1.0f : 0.0f;
                const int pj = pid[jt];
                out_y[e] = (m && pj == mypid && pj > 0) ? 1.0f : 0.0f;

                float* ef = out_ef + e * (2 * DD);
#pragma unroll
                for (int d = 0; d < DD; ++d) ef[d] = m ? diff[d] : 0.0f;
#pragma unroll
                for (int d = 0; d < DD; ++d) ef[DD + d] = m ? sum[d] : 0.0f;
            }
        }
    }

    // dst column of edge_index
    for (int t = tid; t < QQ * KK; t += TPB) {
        out_dst[(long)iA * KK + t] = (float)(iA + t / KK);
    }
}

extern "C" void kernel_launch(void* const* d_in, const int* in_sizes, int n_in,
                              void* d_out, int out_size, void* d_ws, size_t ws_size,
                              hipStream_t stream) {
    const float* x = (const float*)d_in[0];
    const int* pid = (const int*)d_in[1];
    float* out = (float*)d_out;

    float* out_x   = out;                                // N*D
    float* out_src = out_x + NN * DD;                    // N*K
    float* out_dst = out_src + NN * KK;                  // N*K
    float* out_y   = out_dst + NN * KK;                  // N*K
    float* out_ef  = out_y + NN * KK;                    // N*K*2D
    float* out_mask = out_ef + (long)NN * KK * 2 * DD;   // N*K

    // ws layout: sqf f32[NN] | cnt u32[NN] | lists u16[NN][LIST_MAX] (~25.3 MB)
    float* sqf = (float*)d_ws;
    unsigned int* ws_cnt = (unsigned int*)((char*)d_ws + NN * sizeof(float));
    unsigned short* ws_list =
        (unsigned short*)((char*)d_ws + NN * sizeof(float) + NN * sizeof(unsigned int));

    prep_kernel<<<NN / 256, 256, 0, stream>>>(x, out_x, sqf);
    scan_kernel<<<NN / QQ, TPB, 0, stream>>>(x, sqf, ws_cnt, ws_list);
    select_kernel<<<NN / QQ, TPB, 0, stream>>>(x, pid, sqf, ws_cnt, ws_list,
                                               out_src, out_dst, out_y,
                                               out_ef, out_mask);
}

// Round 15
// 425.884 us; speedup vs baseline: 1.7221x; 1.7221x over previous
//
#include <hip/hip_runtime.h>

#define NN 16384
#define DD 16
#define KK 64
#define QQ 4            // queries per block
#define TPB 256
#define NCHUNK 8        // bm word c covers j=(c*8+k)*TPB+tid, bit 4k+q
#define HIST 1024       // buckets over d2 in [0,256), width 1/4 — covers ALL pairs
#define HISTW (HIST/2)  // packed: 2 u16 counters per u32
#define LIST_MAX 768    // E[count]≈590, +7 sigma; overflow -> exact fallback
#define CAND_MAX 256

// XLA:CPU vectorized row-reduce, minor dim 16: lane halving tree. (VALIDATED r5)
__device__ __forceinline__ float halving_sumsq16(const float* v) {
    float p[16];
#pragma unroll
    for (int d = 0; d < 16; ++d) p[d] = __fmul_rn(v[d], v[d]);
    float r8[8];
#pragma unroll
    for (int j = 0; j < 8; ++j) r8[j] = __fadd_rn(p[j], p[j + 8]);
    float r4[4];
#pragma unroll
    for (int j = 0; j < 4; ++j) r4[j] = __fadd_rn(r8[j], r8[j + 4]);
    float r2[2];
#pragma unroll
    for (int j = 0; j < 2; ++j) r2[j] = __fadd_rn(r4[j], r4[j + 2]);
    return __fadd_rn(r2[0], r2[1]);
}

// d2 recipe (VALIDATED r5): f32( f32(sqi+sqj) - 2*dot ), dot = ascending-k fmaf
__device__ __forceinline__ float d2_of(const float* xi, const float* xj,
                                       float sqi, float sqj) {
    float dot = 0.0f;
#pragma unroll
    for (int d = 0; d < DD; ++d) dot = fmaf(xi[d], xj[d], dot);
    return __fsub_rn(__fadd_rn(sqi, sqj), __fmul_rn(2.0f, dot));
}

__device__ __forceinline__ int bucket_of(float d2) {
    int b = (int)__fmul_rn(d2, 4.0f);
    if (b < 0) b = 0;
    if (b >= HIST) b = HIST - 1;
    return b;
}

#define LOAD_XQ()                                                              \
    float xq[QQ][DD];                                                          \
    float sq[QQ], Tq[QQ];                                                      \
    _Pragma("unroll") for (int q = 0; q < QQ; ++q) {                           \
        const float4* p = reinterpret_cast<const float4*>(x + (iA + q) * DD);  \
        float4 a0 = p[0], a1 = p[1], a2 = p[2], a3 = p[3];                     \
        xq[q][0]=a0.x; xq[q][1]=a0.y; xq[q][2]=a0.z; xq[q][3]=a0.w;            \
        xq[q][4]=a1.x; xq[q][5]=a1.y; xq[q][6]=a1.z; xq[q][7]=a1.w;            \
        xq[q][8]=a2.x; xq[q][9]=a2.y; xq[q][10]=a2.z; xq[q][11]=a2.w;          \
        xq[q][12]=a3.x; xq[q][13]=a3.y; xq[q][14]=a3.z; xq[q][15]=a3.w;        \
        sq[q] = sqf[iA + q];                                                   \
        Tq[q] = 16.0f + sq[q] - 1.8f * sqrtf(32.0f + 4.0f * sq[q]);            \
    }

#define LOAD_XJ(j)                                                             \
    const float4* xj4 = reinterpret_cast<const float4*>(x + (j) * DD);         \
    float4 a0 = xj4[0], a1 = xj4[1], a2 = xj4[2], a3 = xj4[3];                 \
    float xj[DD] = {a0.x, a0.y, a0.z, a0.w, a1.x, a1.y, a1.z, a1.w,            \
                    a2.x, a2.y, a2.z, a2.w, a3.x, a3.y, a3.z, a3.w};

// ---------------- prep: f32 squared norms (halving tree) + copy x ----------------
__global__ void prep_kernel(const float* __restrict__ x,
                            float* __restrict__ out_x,
                            float* __restrict__ sqf) {
    int i = blockIdx.x * blockDim.x + threadIdx.x;
    if (i < NN) {
        float v[DD];
#pragma unroll
        for (int d = 0; d < DD; ++d) v[d] = x[i * DD + d];
        sqf[i] = halving_sumsq16(v);
    }
    for (int t = i; t < NN * DD; t += gridDim.x * blockDim.x) {
        out_x[t] = x[t];
    }
}

// ---------------- K1: silent scan (bits->LDS once per 8 j) + one-time harvest ----------------
__global__ __launch_bounds__(TPB, 4) void scan_kernel(
        const float* __restrict__ x,
        const float* __restrict__ sqf,
        unsigned int* __restrict__ ws_cnt,
        unsigned short* __restrict__ ws_list) {
    __shared__ unsigned int bm[NCHUNK][TPB];        // 8 KB want-bitmask
    __shared__ unsigned short list[QQ][LIST_MAX];   // 6 KB
    __shared__ unsigned int wcnt[TPB / 64][QQ];
    __shared__ unsigned int s_listcnt[QQ];

    const int bid = blockIdx.x;
    const int tid = threadIdx.x;
    const int lane = tid & 63;
    const int w = tid >> 6;
    const int iA = bid * QQ;

    LOAD_XQ();

    // hot loop: pure VALU + VMEM; 1 ds_write per 8 j; bounded unroll (VGPR-safe)
#pragma unroll 1
    for (int c = 0; c < NCHUNK; ++c) {
        unsigned int bits = 0;
#pragma unroll
        for (int k = 0; k < 8; ++k) {
            const int j = (c * 8 + k) * TPB + tid;
            LOAD_XJ(j);
            const float sj = sqf[j];
#pragma unroll
            for (int q = 0; q < QQ; ++q) {
                float d2 = d2_of(xq[q], xj, sq[q], sj);
                if (d2 < Tq[q]) bits |= (1u << (4 * k + q));
            }
        }
        bm[c][tid] = bits;
    }
    __syncthreads();

    // one-time harvest (r12-B2 logic, validated): popc -> wave prefix -> scatter
    {
        unsigned int cnt[QQ] = {0, 0, 0, 0};
#pragma unroll 1
        for (int c = 0; c < NCHUNK; ++c) {
            unsigned int w32 = bm[c][tid];
#pragma unroll
            for (int q = 0; q < QQ; ++q)
                cnt[q] += (unsigned int)__popc(w32 & (0x11111111u << q));
        }
        unsigned int excl[QQ];
#pragma unroll
        for (int q = 0; q < QQ; ++q) {
            unsigned int v = cnt[q];
#pragma unroll
            for (int off = 1; off < 64; off <<= 1) {
                unsigned int n = __shfl_up(v, off, 64);
                if (lane >= off) v += n;
            }
            excl[q] = v - cnt[q];
            if (lane == 63) wcnt[w][q] = v;
        }
        __syncthreads();
        if (tid < QQ)
            s_listcnt[tid] = wcnt[0][tid] + wcnt[1][tid] + wcnt[2][tid] + wcnt[3][tid];
        unsigned int cur[QQ];
#pragma unroll
        for (int q = 0; q < QQ; ++q) {
            unsigned int b = 0;
            for (int ww = 0; ww < w; ++ww) b += wcnt[ww][q];
            cur[q] = b + excl[q];
        }
#pragma unroll 1
        for (int c = 0; c < NCHUNK; ++c) {
            unsigned int t32 = bm[c][tid];
            while (t32) {
                int b = __ffs(t32) - 1;
                int q = b & 3;
                int k = b >> 2;
                unsigned int pos = cur[q]++;
                if (pos < LIST_MAX)
                    list[q][pos] = (unsigned short)((c * 8 + k) * TPB + tid);
                t32 &= t32 - 1;
            }
        }
    }
    __syncthreads();

    // dump lists + raw counts to ws
    for (int q = 0; q < QQ; ++q) {
        int lc = (int)min(s_listcnt[q], (unsigned int)LIST_MAX);
        unsigned short* dst = ws_list + ((long)iA + q) * LIST_MAX;
        for (int e = tid; e < lc; e += TPB) dst[e] = list[q][e];
    }
    if (tid < QQ) ws_cnt[iA + tid] = s_listcnt[tid];
}

// ---------------- K2: select + rank + write (VALIDATED r13, unchanged) ----------------
__global__ __launch_bounds__(TPB) void select_kernel(
        const float* __restrict__ x,
        const int* __restrict__ pid,
        const float* __restrict__ sqf,
        const unsigned int* __restrict__ ws_cnt,
        const unsigned short* __restrict__ ws_list,
        float* __restrict__ out_src,
        float* __restrict__ out_dst,
        float* __restrict__ out_y,
        float* __restrict__ out_ef,
        float* __restrict__ out_mask) {
    __shared__ unsigned short list[QQ][LIST_MAX];   // 6 KB
    __shared__ unsigned int hist[QQ][HISTW];        // 8 KB
    __shared__ unsigned int cand_key[QQ][CAND_MAX]; // 4 KB
    __shared__ int cand_idx[QQ][CAND_MAX];          // 4 KB
    __shared__ unsigned int wavesum[QQ][TPB / 64];
    __shared__ int s_bsel[QQ];
    __shared__ unsigned int s_excnt[QQ], s_candcnt[QQ], s_lc[QQ];
    __shared__ int s_fb[QQ];

    const int bid = blockIdx.x;
    const int tid = threadIdx.x;
    const int lane = tid & 63;
    const int w = tid >> 6;
    const int iA = bid * QQ;

    for (int t = tid; t < QQ * HISTW; t += TPB)
        ((unsigned int*)hist)[t] = 0;
    if (tid < QQ) {
        s_excnt[tid] = 0; s_candcnt[tid] = 0; s_bsel[tid] = HIST - 1;
        s_lc[tid] = min(ws_cnt[iA + tid], (unsigned int)LIST_MAX);
    }
    LOAD_XQ();
    __syncthreads();

    for (int q = 0; q < QQ; ++q) {
        const unsigned short* src = ws_list + ((long)iA + q) * LIST_MAX;
        const int lc = (int)s_lc[q];
        for (int e = tid; e < lc; e += TPB) list[q][e] = src[e];
    }
    __syncthreads();

    // E0: exact d2 per list entry -> hist + exact count(<Tq) soundness guard
    for (int q = 0; q < QQ; ++q) {
        const int lc = (int)s_lc[q];
        unsigned int my = 0;
        for (int e = tid; e < lc; e += TPB) {
            const int j = list[q][e];
            LOAD_XJ(j);
            float d2 = d2_of(xq[q], xj, sq[q], sqf[j]);
            my += (d2 < Tq[q]) ? 1u : 0u;
            int b = bucket_of(d2);
            atomicAdd(&hist[q][b >> 1], 1u << ((b & 1) << 4));
        }
        unsigned int v = my;
#pragma unroll
        for (int off = 1; off < 64; off <<= 1) v += __shfl_xor(v, off, 64);
        if (lane == 0 && v) atomicAdd(&s_excnt[q], v);
    }
    __syncthreads();

    if (tid < QQ)
        s_fb[tid] = (ws_cnt[iA + tid] > LIST_MAX) || (s_excnt[tid] < KK + 1);
    __syncthreads();
    const int anyfb = s_fb[0] | s_fb[1] | s_fb[2] | s_fb[3];

    if (anyfb) {
#pragma unroll
        for (int q = 0; q < QQ; ++q)
            if (s_fb[q])
                for (int t = tid; t < HISTW; t += TPB) hist[q][t] = 0;
        __syncthreads();
        for (int j = tid; j < NN; j += TPB) {
            LOAD_XJ(j);
            const float sj = sqf[j];
#pragma unroll
            for (int q = 0; q < QQ; ++q) {
                if (s_fb[q] && j != iA + q) {
                    float d2 = d2_of(xq[q], xj, sq[q], sj);
                    int b = bucket_of(d2);
                    atomicAdd(&hist[q][b >> 1], 1u << ((b & 1) << 4));
                }
            }
        }
    }
    __syncthreads();

    // F: prefix-scan over packed buckets -> bucket of need-th key (VALIDATED)
    {
        unsigned int local[QQ], inc[QQ];
        unsigned int pc0[QQ], pc1[QQ], pc2[QQ], pc3[QQ];
#pragma unroll
        for (int q = 0; q < QQ; ++q) {
            unsigned int h0 = hist[q][2 * tid];
            unsigned int h1 = hist[q][2 * tid + 1];
            pc0[q] = h0 & 0xFFFFu; pc1[q] = h0 >> 16;
            pc2[q] = h1 & 0xFFFFu; pc3[q] = h1 >> 16;
            unsigned int s = pc0[q] + pc1[q] + pc2[q] + pc3[q];
            local[q] = s;
            unsigned int v = s;
#pragma unroll
            for (int off = 1; off < 64; off <<= 1) {
                unsigned int n = __shfl_up(v, off, 64);
                if (lane >= off) v += n;
            }
            inc[q] = v;
        }
        if (lane == 63)
#pragma unroll
            for (int q = 0; q < QQ; ++q) wavesum[q][w] = inc[q];
        __syncthreads();
#pragma unroll
        for (int q = 0; q < QQ; ++q) {
            const unsigned int need = s_fb[q] ? KK : (KK + 1);
            unsigned int woff = 0;
            for (int ww = 0; ww < w; ++ww) woff += wavesum[q][ww];
            unsigned int cum = inc[q] + woff;
            unsigned int prev = cum - local[q];
            if (prev < need && need <= cum) {
                unsigned int acc = prev;
                int b = 4 * tid;
                if (acc + pc0[q] < need) { acc += pc0[q]; ++b;
                    if (acc + pc1[q] < need) { acc += pc1[q]; ++b;
                        if (acc + pc2[q] < need) { acc += pc2[q]; ++b; } } }
                s_bsel[q] = b;
            }
        }
    }
    __syncthreads();

    // G: candidate gather (self excluded)
#pragma unroll
    for (int q = 0; q < QQ; ++q) {
        if (!s_fb[q]) {
            const int bsel = s_bsel[q];
            const int lc = (int)s_lc[q];
            for (int e = tid; e < lc; e += TPB) {
                const int j = list[q][e];
                LOAD_XJ(j);
                float d2 = d2_of(xq[q], xj, sq[q], sqf[j]);
                if (bucket_of(d2) <= bsel && j != iA + q) {
                    unsigned int pos = atomicAdd(&s_candcnt[q], 1u);
                    if (pos < CAND_MAX) {
                        unsigned int u = __float_as_uint(d2);
                        u ^= (u & 0x80000000u) ? 0xFFFFFFFFu : 0x80000000u;
                        cand_key[q][pos] = u;
                        cand_idx[q][pos] = j;
                    }
                }
            }
        }
    }
    if (anyfb) {
        for (int j = tid; j < NN; j += TPB) {
            LOAD_XJ(j);
            const float sj = sqf[j];
#pragma unroll
            for (int q = 0; q < QQ; ++q) {
                if (s_fb[q] && j != iA + q) {
                    float d2 = d2_of(xq[q], xj, sq[q], sj);
                    if (bucket_of(d2) <= s_bsel[q]) {
                        unsigned int pos = atomicAdd(&s_candcnt[q], 1u);
                        if (pos < CAND_MAX) {
                            unsigned int u = __float_as_uint(d2);
                            u ^= (u & 0x80000000u) ? 0xFFFFFFFFu : 0x80000000u;
                            cand_key[q][pos] = u;
                            cand_idx[q][pos] = j;
                        }
                    }
                }
            }
        }
    }
    __syncthreads();

    // H: rank by (key asc, index asc) + write outputs (VALIDATED)
    for (int q = 0; q < QQ; ++q) {
        const int iq = iA + q;
        const int mypid = pid[iq];
        int c = (int)s_candcnt[q];
        if (c > CAND_MAX) c = CAND_MAX;
        for (int t = tid; t < c; t += TPB) {
            const unsigned int kt = cand_key[q][t];
            const int jt = cand_idx[q][t];
            int rank = 0;
            for (int u = 0; u < c; ++u) {
                unsigned int ku = cand_key[q][u];
                rank += (ku < kt) || (ku == kt && cand_idx[q][u] < jt);
            }
            if (rank < KK) {
                const long e = (long)iq * KK + rank;
                out_src[e] = (float)jt;

                const float* xjp = x + jt * DD;
                float diff[DD], sum[DD];
#pragma unroll
                for (int d = 0; d < DD; ++d) {
                    float a = xjp[d], b = xq[q][d];
                    diff[d] = __fsub_rn(a, b);   // x_src - x_dst
                    sum[d]  = __fadd_rn(a, b);   // x_src + x_dst
                }
                const float s2 = halving_sumsq16(diff);    // VALIDATED tree
                const bool m = __fsqrt_rn(s2) < 6.0f;
                out_mask[e] = m ? 1.0f : 0.0f;
                const int pj = pid[jt];
                out_y[e] = (m && pj == mypid && pj > 0) ? 1.0f : 0.0f;

                float* ef = out_ef + e * (2 * DD);
#pragma unroll
                for (int d = 0; d < DD; ++d) ef[d] = m ? diff[d] : 0.0f;
#pragma unroll
                for (int d = 0; d < DD; ++d) ef[DD + d] = m ? sum[d] : 0.0f;
            }
        }
    }

    // dst column of edge_index
    for (int t = tid; t < QQ * KK; t += TPB) {
        out_dst[(long)iA * KK + t] = (float)(iA + t / KK);
    }
}

extern "C" void kernel_launch(void* const* d_in, const int* in_sizes, int n_in,
                              void* d_out, int out_size, void* d_ws, size_t ws_size,
                              hipStream_t stream) {
    const float* x = (const float*)d_in[0];
    const int* pid = (const int*)d_in[1];
    float* out = (float*)d_out;

    float* out_x   = out;                                // N*D
    float* out_src = out_x + NN * DD;                    // N*K
    float* out_dst = out_src + NN * KK;                  // N*K
    float* out_y   = out_dst + NN * KK;                  // N*K
    float* out_ef  = out_y + NN * KK;                    // N*K*2D
    float* out_mask = out_ef + (long)NN * KK * 2 * DD;   // N*K

    // ws layout: sqf f32[NN] | cnt u32[NN] | lists u16[NN][LIST_MAX] (~25.3 MB)
    float* sqf = (float*)d_ws;
    unsigned int* ws_cnt = (unsigned int*)((char*)d_ws + NN * sizeof(float));
    unsigned short* ws_list =
        (unsigned short*)((char*)d_ws + NN * sizeof(float) + NN * sizeof(unsigned int));

    prep_kernel<<<NN / 256, 256, 0, stream>>>(x, out_x, sqf);
    scan_kernel<<<NN / QQ, TPB, 0, stream>>>(x, sqf, ws_cnt, ws_list);
    select_kernel<<<NN / QQ, TPB, 0, stream>>>(x, pid, sqf, ws_cnt, ws_list,
                                               out_src, out_dst, out_y,
                                               out_ef, out_mask);
}

// Round 16
// 374.913 us; speedup vs baseline: 1.9563x; 1.1360x over previous
//
#include <hip/hip_runtime.h>

#define NN 16384
#define DD 16
#define KK 64
#define QQ 4            // queries per block
#define TPB 256
#define NQW 16          // bm words/thread; word c = quad c*TPB+tid, bit jl*4+q
#define HIST 1024       // buckets over d2 in [0,256), width 1/4 — covers ALL pairs
#define HISTW (HIST/2)  // packed: 2 u16 counters per u32
#define LIST_MAX 768    // E[count]≈590, +7 sigma; overflow -> exact fallback
#define CAND_MAX 256

// XLA:CPU vectorized row-reduce, minor dim 16: lane halving tree. (VALIDATED r5)
__device__ __forceinline__ float halving_sumsq16(const float* v) {
    float p[16];
#pragma unroll
    for (int d = 0; d < 16; ++d) p[d] = __fmul_rn(v[d], v[d]);
    float r8[8];
#pragma unroll
    for (int j = 0; j < 8; ++j) r8[j] = __fadd_rn(p[j], p[j + 8]);
    float r4[4];
#pragma unroll
    for (int j = 0; j < 4; ++j) r4[j] = __fadd_rn(r8[j], r8[j + 4]);
    float r2[2];
#pragma unroll
    for (int j = 0; j < 2; ++j) r2[j] = __fadd_rn(r4[j], r4[j + 2]);
    return __fadd_rn(r2[0], r2[1]);
}

// d2 recipe (VALIDATED r5): f32( f32(sqi+sqj) - 2*dot ), dot = ascending-k fmaf
__device__ __forceinline__ float d2_of(const float* xi, const float* xj,
                                       float sqi, float sqj) {
    float dot = 0.0f;
#pragma unroll
    for (int d = 0; d < DD; ++d) dot = fmaf(xi[d], xj[d], dot);
    return __fsub_rn(__fadd_rn(sqi, sqj), __fmul_rn(2.0f, dot));
}

__device__ __forceinline__ int bucket_of(float d2) {
    int b = (int)__fmul_rn(d2, 4.0f);
    if (b < 0) b = 0;
    if (b >= HIST) b = HIST - 1;
    return b;
}

#define LOAD_XQ()                                                              \
    float xq[QQ][DD];                                                          \
    float sq[QQ], Tq[QQ];                                                      \
    _Pragma("unroll") for (int q = 0; q < QQ; ++q) {                           \
        const float4* p = reinterpret_cast<const float4*>(x + (iA + q) * DD);  \
        float4 a0 = p[0], a1 = p[1], a2 = p[2], a3 = p[3];                     \
        xq[q][0]=a0.x; xq[q][1]=a0.y; xq[q][2]=a0.z; xq[q][3]=a0.w;            \
        xq[q][4]=a1.x; xq[q][5]=a1.y; xq[q][6]=a1.z; xq[q][7]=a1.w;            \
        xq[q][8]=a2.x; xq[q][9]=a2.y; xq[q][10]=a2.z; xq[q][11]=a2.w;          \
        xq[q][12]=a3.x; xq[q][13]=a3.y; xq[q][14]=a3.z; xq[q][15]=a3.w;        \
        sq[q] = sqf[iA + q];                                                   \
        Tq[q] = 16.0f + sq[q] - 1.8f * sqrtf(32.0f + 4.0f * sq[q]);            \
    }

#define LOAD_XJ(j)                                                             \
    const float4* xj4 = reinterpret_cast<const float4*>(x + (j) * DD);         \
    float4 a0 = xj4[0], a1 = xj4[1], a2 = xj4[2], a3 = xj4[3];                 \
    float xj[DD] = {a0.x, a0.y, a0.z, a0.w, a1.x, a1.y, a1.z, a1.w,            \
                    a2.x, a2.y, a2.z, a2.w, a3.x, a3.y, a3.z, a3.w};

// ---------------- prep: norms + copy x + transpose x -> xt[d][j] ----------------
__global__ void prep_kernel(const float* __restrict__ x,
                            float* __restrict__ out_x,
                            float* __restrict__ sqf,
                            float* __restrict__ xt) {
    int i = blockIdx.x * blockDim.x + threadIdx.x;
    if (i < NN) {
        float v[DD];
#pragma unroll
        for (int d = 0; d < DD; ++d) v[d] = x[i * DD + d];
        sqf[i] = halving_sumsq16(v);
#pragma unroll
        for (int d = 0; d < DD; ++d) xt[d * NN + i] = v[d];   // coalesced per d
    }
    for (int t = i; t < NN * DD; t += gridDim.x * blockDim.x) {
        out_x[t] = x[t];
    }
}

// ---------------- K1: transposed coalesced scan + one-time harvest ----------------
__global__ __launch_bounds__(TPB, 6) void scan_kernel(
        const float* __restrict__ x,
        const float* __restrict__ xt,
        const float* __restrict__ sqf,
        unsigned int* __restrict__ ws_cnt,
        unsigned short* __restrict__ ws_list) {
    __shared__ unsigned short bm[NQW][TPB];         // 8 KB want-bits (u16/quad)
    __shared__ unsigned short list[QQ][LIST_MAX];   // 6 KB
    __shared__ unsigned int wcnt[TPB / 64][QQ];
    __shared__ unsigned int s_listcnt[QQ];

    const int bid = blockIdx.x;
    const int tid = threadIdx.x;
    const int lane = tid & 63;
    const int w = tid >> 6;
    const int iA = bid * QQ;

    LOAD_XQ();

    // hot loop: per iteration one quad of 4 consecutive j.
    // 16 float4 loads at 16B lane stride = fully coalesced (16 lines/instr).
    // Each j's dot is its own ascending-d fmaf chain (bit-exact, VALIDATED).
#pragma unroll 1
    for (int c = 0; c < NQW; ++c) {
        const int qd = c * TPB + tid;               // quad index; j = 4*qd + jl
        float4 sjv = reinterpret_cast<const float4*>(sqf)[qd];
        float4 acc[QQ];
#pragma unroll
        for (int q = 0; q < QQ; ++q) acc[q] = make_float4(0.f, 0.f, 0.f, 0.f);
#pragma unroll
        for (int d = 0; d < DD; ++d) {
            float4 xv = reinterpret_cast<const float4*>(xt + (long)d * NN)[qd];
#pragma unroll
            for (int q = 0; q < QQ; ++q) {
                acc[q].x = fmaf(xq[q][d], xv.x, acc[q].x);
                acc[q].y = fmaf(xq[q][d], xv.y, acc[q].y);
                acc[q].z = fmaf(xq[q][d], xv.z, acc[q].z);
                acc[q].w = fmaf(xq[q][d], xv.w, acc[q].w);
            }
        }
        unsigned int bits = 0;
#pragma unroll
        for (int q = 0; q < QQ; ++q) {
            float d2x = __fsub_rn(__fadd_rn(sq[q], sjv.x), __fmul_rn(2.0f, acc[q].x));
            float d2y = __fsub_rn(__fadd_rn(sq[q], sjv.y), __fmul_rn(2.0f, acc[q].y));
            float d2z = __fsub_rn(__fadd_rn(sq[q], sjv.z), __fmul_rn(2.0f, acc[q].z));
            float d2w = __fsub_rn(__fadd_rn(sq[q], sjv.w), __fmul_rn(2.0f, acc[q].w));
            if (d2x < Tq[q]) bits |= (1u << (0 * 4 + q));
            if (d2y < Tq[q]) bits |= (1u << (1 * 4 + q));
            if (d2z < Tq[q]) bits |= (1u << (2 * 4 + q));
            if (d2w < Tq[q]) bits |= (1u << (3 * 4 + q));
        }
        bm[c][tid] = (unsigned short)bits;
    }
    __syncthreads();

    // one-time harvest (validated pattern): popc -> wave prefix -> scatter
    {
        unsigned int cnt[QQ] = {0, 0, 0, 0};
#pragma unroll 1
        for (int c = 0; c < NQW; ++c) {
            unsigned int w16 = bm[c][tid];
#pragma unroll
            for (int q = 0; q < QQ; ++q)
                cnt[q] += (unsigned int)__popc(w16 & (0x1111u << q));
        }
        unsigned int excl[QQ];
#pragma unroll
        for (int q = 0; q < QQ; ++q) {
            unsigned int v = cnt[q];
#pragma unroll
            for (int off = 1; off < 64; off <<= 1) {
                unsigned int n = __shfl_up(v, off, 64);
                if (lane >= off) v += n;
            }
            excl[q] = v - cnt[q];
            if (lane == 63) wcnt[w][q] = v;
        }
        __syncthreads();
        if (tid < QQ)
            s_listcnt[tid] = wcnt[0][tid] + wcnt[1][tid] + wcnt[2][tid] + wcnt[3][tid];
        unsigned int cur[QQ];
#pragma unroll
        for (int q = 0; q < QQ; ++q) {
            unsigned int b = 0;
            for (int ww = 0; ww < w; ++ww) b += wcnt[ww][q];
            cur[q] = b + excl[q];
        }
#pragma unroll 1
        for (int c = 0; c < NQW; ++c) {
            unsigned int t16 = bm[c][tid];
            while (t16) {
                int b = __ffs(t16) - 1;
                int q = b & 3;
                int jl = b >> 2;
                unsigned int pos = cur[q]++;
                if (pos < LIST_MAX)
                    list[q][pos] = (unsigned short)((c * TPB + tid) * 4 + jl);
                t16 &= t16 - 1;
            }
        }
    }
    __syncthreads();

    // dump lists + raw counts to ws
    for (int q = 0; q < QQ; ++q) {
        int lc = (int)min(s_listcnt[q], (unsigned int)LIST_MAX);
        unsigned short* dst = ws_list + ((long)iA + q) * LIST_MAX;
        for (int e = tid; e < lc; e += TPB) dst[e] = list[q][e];
    }
    if (tid < QQ) ws_cnt[iA + tid] = s_listcnt[tid];
}

// ---------------- K2: select + rank + write (VALIDATED r13/r15, unchanged) ----------------
__global__ __launch_bounds__(TPB) void select_kernel(
        const float* __restrict__ x,
        const int* __restrict__ pid,
        const float* __restrict__ sqf,
        const unsigned int* __restrict__ ws_cnt,
        const unsigned short* __restrict__ ws_list,
        float* __restrict__ out_src,
        float* __restrict__ out_dst,
        float* __restrict__ out_y,
        float* __restrict__ out_ef,
        float* __restrict__ out_mask) {
    __shared__ unsigned short list[QQ][LIST_MAX];   // 6 KB
    __shared__ unsigned int hist[QQ][HISTW];        // 8 KB
    __shared__ unsigned int cand_key[QQ][CAND_MAX]; // 4 KB
    __shared__ int cand_idx[QQ][CAND_MAX];          // 4 KB
    __shared__ unsigned int wavesum[QQ][TPB / 64];
    __shared__ int s_bsel[QQ];
    __shared__ unsigned int s_excnt[QQ], s_candcnt[QQ], s_lc[QQ];
    __shared__ int s_fb[QQ];

    const int bid = blockIdx.x;
    const int tid = threadIdx.x;
    const int lane = tid & 63;
    const int w = tid >> 6;
    const int iA = bid * QQ;

    for (int t = tid; t < QQ * HISTW; t += TPB)
        ((unsigned int*)hist)[t] = 0;
    if (tid < QQ) {
        s_excnt[tid] = 0; s_candcnt[tid] = 0; s_bsel[tid] = HIST - 1;
        s_lc[tid] = min(ws_cnt[iA + tid], (unsigned int)LIST_MAX);
    }
    LOAD_XQ();
    __syncthreads();

    for (int q = 0; q < QQ; ++q) {
        const unsigned short* src = ws_list + ((long)iA + q) * LIST_MAX;
        const int lc = (int)s_lc[q];
        for (int e = tid; e < lc; e += TPB) list[q][e] = src[e];
    }
    __syncthreads();

    // E0: exact d2 per list entry -> hist + exact count(<Tq) soundness guard
    for (int q = 0; q < QQ; ++q) {
        const int lc = (int)s_lc[q];
        unsigned int my = 0;
        for (int e = tid; e < lc; e += TPB) {
            const int j = list[q][e];
            LOAD_XJ(j);
            float d2 = d2_of(xq[q], xj, sq[q], sqf[j]);
            my += (d2 < Tq[q]) ? 1u : 0u;
            int b = bucket_of(d2);
            atomicAdd(&hist[q][b >> 1], 1u << ((b & 1) << 4));
        }
        unsigned int v = my;
#pragma unroll
        for (int off = 1; off < 64; off <<= 1) v += __shfl_xor(v, off, 64);
        if (lane == 0 && v) atomicAdd(&s_excnt[q], v);
    }
    __syncthreads();

    if (tid < QQ)
        s_fb[tid] = (ws_cnt[iA + tid] > LIST_MAX) || (s_excnt[tid] < KK + 1);
    __syncthreads();
    const int anyfb = s_fb[0] | s_fb[1] | s_fb[2] | s_fb[3];

    if (anyfb) {
#pragma unroll
        for (int q = 0; q < QQ; ++q)
            if (s_fb[q])
                for (int t = tid; t < HISTW; t += TPB) hist[q][t] = 0;
        __syncthreads();
        for (int j = tid; j < NN; j += TPB) {
            LOAD_XJ(j);
            const float sj = sqf[j];
#pragma unroll
            for (int q = 0; q < QQ; ++q) {
                if (s_fb[q] && j != iA + q) {
                    float d2 = d2_of(xq[q], xj, sq[q], sj);
                    int b = bucket_of(d2);
                    atomicAdd(&hist[q][b >> 1], 1u << ((b & 1) << 4));
                }
            }
        }
    }
    __syncthreads();

    // F: prefix-scan over packed buckets -> bucket of need-th key (VALIDATED)
    {
        unsigned int local[QQ], inc[QQ];
        unsigned int pc0[QQ], pc1[QQ], pc2[QQ], pc3[QQ];
#pragma unroll
        for (int q = 0; q < QQ; ++q) {
            unsigned int h0 = hist[q][2 * tid];
            unsigned int h1 = hist[q][2 * tid + 1];
            pc0[q] = h0 & 0xFFFFu; pc1[q] = h0 >> 16;
            pc2[q] = h1 & 0xFFFFu; pc3[q] = h1 >> 16;
            unsigned int s = pc0[q] + pc1[q] + pc2[q] + pc3[q];
            local[q] = s;
            unsigned int v = s;
#pragma unroll
            for (int off = 1; off < 64; off <<= 1) {
                unsigned int n = __shfl_up(v, off, 64);
                if (lane >= off) v += n;
            }
            inc[q] = v;
        }
        if (lane == 63)
#pragma unroll
            for (int q = 0; q < QQ; ++q) wavesum[q][w] = inc[q];
        __syncthreads();
#pragma unroll
        for (int q = 0; q < QQ; ++q) {
            const unsigned int need = s_fb[q] ? KK : (KK + 1);
            unsigned int woff = 0;
            for (int ww = 0; ww < w; ++ww) woff += wavesum[q][ww];
            unsigned int cum = inc[q] + woff;
            unsigned int prev = cum - local[q];
            if (prev < need && need <= cum) {
                unsigned int acc = prev;
                int b = 4 * tid;
                if (acc + pc0[q] < need) { acc += pc0[q]; ++b;
                    if (acc + pc1[q] < need) { acc += pc1[q]; ++b;
                        if (acc + pc2[q] < need) { acc += pc2[q]; ++b; } } }
                s_bsel[q] = b;
            }
        }
    }
    __syncthreads();

    // G: candidate gather (self excluded)
#pragma unroll
    for (int q = 0; q < QQ; ++q) {
        if (!s_fb[q]) {
            const int bsel = s_bsel[q];
            const int lc = (int)s_lc[q];
            for (int e = tid; e < lc; e += TPB) {
                const int j = list[q][e];
                LOAD_XJ(j);
                float d2 = d2_of(xq[q], xj, sq[q], sqf[j]);
                if (bucket_of(d2) <= bsel && j != iA + q) {
                    unsigned int pos = atomicAdd(&s_candcnt[q], 1u);
                    if (pos < CAND_MAX) {
                        unsigned int u = __float_as_uint(d2);
                        u ^= (u & 0x80000000u) ? 0xFFFFFFFFu : 0x80000000u;
                        cand_key[q][pos] = u;
                        cand_idx[q][pos] = j;
                    }
                }
            }
        }
    }
    if (anyfb) {
        for (int j = tid; j < NN; j += TPB) {
            LOAD_XJ(j);
            const float sj = sqf[j];
#pragma unroll
            for (int q = 0; q < QQ; ++q) {
                if (s_fb[q] && j != iA + q) {
                    float d2 = d2_of(xq[q], xj, sq[q], sj);
                    if (bucket_of(d2) <= s_bsel[q]) {
                        unsigned int pos = atomicAdd(&s_candcnt[q], 1u);
                        if (pos < CAND_MAX) {
                            unsigned int u = __float_as_uint(d2);
                            u ^= (u & 0x80000000u) ? 0xFFFFFFFFu : 0x80000000u;
                            cand_key[q][pos] = u;
                            cand_idx[q][pos] = j;
                        }
                    }
                }
            }
        }
    }
    __syncthreads();

    // H: rank by (key asc, index asc) + write outputs (VALIDATED)
    for (int q = 0; q < QQ; ++q) {
        const int iq = iA + q;
        const int mypid = pid[iq];
        int c = (int)s_candcnt[q];
        if (c > CAND_MAX) c = CAND_MAX;
        for (int t = tid; t < c; t += TPB) {
            const unsigned int kt = cand_key[q][t];
            const int jt = cand_idx[q][t];
            int rank = 0;
            for (int u = 0; u < c; ++u) {
                unsigned int ku = cand_key[q][u];
                rank += (ku < kt) || (ku == kt && cand_idx[q][u] < jt);
            }
            if (rank < KK) {
                const long e = (long)iq * KK + rank;
                out_src[e] = (float)jt;

                const float* xjp = x + jt * DD;
                float diff[DD], sum[DD];
#pragma unroll
                for (int d = 0; d < DD; ++d) {
                    float a = xjp[d], b = xq[q][d];
                    diff[d] = __fsub_rn(a, b);   // x_src - x_dst
                    sum[d]  = __fadd_rn(a, b);   // x_src + x_dst
                }
                const float s2 = halving_sumsq16(diff);    // VALIDATED tree
                const bool m = __fsqrt_rn(s2) < 6.0f;
                out_mask[e] = m ? 1.0f : 0.0f;
                const int pj = pid[jt];
                out_y[e] = (m && pj == mypid && pj > 0) ? 1.0f : 0.0f;

                float* ef = out_ef + e * (2 * DD);
#pragma unroll
                for (int d = 0; d < DD; ++d) ef[d] = m ? diff[d] : 0.0f;
#pragma unroll
                for (int d = 0; d < DD; ++d) ef[DD + d] = m ? sum[d] : 0.0f;
            }
        }
    }

    // dst column of edge_index
    for (int t = tid; t < QQ * KK; t += TPB) {
        out_dst[(long)iA * KK + t] = (float)(iA + t / KK);
    }
}

extern "C" void kernel_launch(void* const* d_in, const int* in_sizes, int n_in,
                              void* d_out, int out_size, void* d_ws, size_t ws_size,
                              hipStream_t stream) {
    const float* x = (const float*)d_in[0];
    const int* pid = (const int*)d_in[1];
    float* out = (float*)d_out;

    float* out_x   = out;                                // N*D
    float* out_src = out_x + NN * DD;                    // N*K
    float* out_dst = out_src + NN * KK;                  // N*K
    float* out_y   = out_dst + NN * KK;                  // N*K
    float* out_ef  = out_y + NN * KK;                    // N*K*2D
    float* out_mask = out_ef + (long)NN * KK * 2 * DD;   // N*K

    // ws layout: sqf f32[NN] | xt f32[DD*NN] | cnt u32[NN] | lists u16[NN][LIST_MAX]
    char* wsb = (char*)d_ws;
    float* sqf = (float*)wsb;
    float* xt = (float*)(wsb + (long)NN * 4);
    unsigned int* ws_cnt = (unsigned int*)(wsb + (long)NN * 4 + (long)NN * DD * 4);
    unsigned short* ws_list =
        (unsigned short*)(wsb + (long)NN * 4 + (long)NN * DD * 4 + (long)NN * 4);

    prep_kernel<<<NN / 256, 256, 0, stream>>>(x, out_x, sqf, xt);
    scan_kernel<<<NN / QQ, TPB, 0, stream>>>(x, xt, sqf, ws_cnt, ws_list);
    select_kernel<<<NN / QQ, TPB, 0, stream>>>(x, pid, sqf, ws_cnt, ws_list,
                                               out_src, out_dst, out_y,
                                               out_ef, out_mask);
}